// Round 1
// baseline (585.934 us; speedup 1.0000x reference)
//
#include <hip/hip_runtime.h>

// ---------------------------------------------------------------------------
// Def_DownSampling: conv3d(3^3,SAME)+bias -> avgpool2 -> gaussian-weighted
// normalized coordinate field -> grid_sample. Key structural facts:
//  * gaus_w is the same kernel for every (oc,ic) => all gaussian-conv output
//    channels are identical and equal G(sum_c D[b,c]).
//  * conv+avgpool fold into one stride-2 4^3 conv (W4 = w (*) box2 / 8).
// Outputs (flat, in order): y (2,32,32,32,32) | D (2,32,32,32,32) |
//                           grid-mean (2,32,32,32,3)
// ---------------------------------------------------------------------------

#define XN 64          // input spatial
#define DN 32          // pooled spatial
#define C  32          // channels

// ---- K0: build W4[ic][u=(uz,uy,ux) 4^3][oc] = (1/8) sum_{s in {0,1}^3} w[oc][ic][u-s]
__global__ __launch_bounds__(256) void k_build_w4(const float* __restrict__ conv_w,
                                                  float* __restrict__ w4) {
    int i = blockIdx.x * 256 + threadIdx.x;          // 32*64*32 = 65536
    if (i >= C * 64 * C) return;
    int oc = i & 31;
    int u  = (i >> 5) & 63;
    int ic = i >> 11;
    int uz = u >> 4, uy = (u >> 2) & 3, ux = u & 3;
    float s = 0.f;
    #pragma unroll
    for (int sz = 0; sz < 2; ++sz) {
        int tz = uz - sz; if (tz < 0 || tz > 2) continue;
        #pragma unroll
        for (int sy = 0; sy < 2; ++sy) {
            int ty = uy - sy; if (ty < 0 || ty > 2) continue;
            #pragma unroll
            for (int sx = 0; sx < 2; ++sx) {
                int tx = ux - sx; if (tx < 0 || tx > 2) continue;
                s += conv_w[(oc * C + ic) * 27 + tz * 9 + ty * 3 + tx];
            }
        }
    }
    w4[i] = 0.125f * s;
}

// ---- K1: stride-2 4^3 conv (+bias) -> D and Dsum
// Block: 128 threads, tile (TZ,TY,TX)=(4,4,8) output positions, all 32 oc per thread.
#define TZ 4
#define TY 4
#define TX 8
#define ITZ (2*TZ + 2)   // 10
#define ITY (2*TY + 2)   // 10
#define ITX (2*TX + 2)   // 18
#define ITILE (ITZ * ITY * ITX)  // 1800

__global__ __launch_bounds__(128) void k_conv_pool(const float* __restrict__ x,
                                                   const float* __restrict__ w4,
                                                   const float* __restrict__ bias,
                                                   float* __restrict__ Dout,
                                                   float* __restrict__ Dsum) {
    __shared__ float tile[ITILE];
    int bid = blockIdx.x;
    int xt = bid & 3;  bid >>= 2;   // 32/8 = 4
    int yt = bid & 7;  bid >>= 3;   // 32/4 = 8
    int zt = bid & 7;  bid >>= 3;   // 32/4 = 8
    int b  = bid;                   // 2
    int z0 = zt * TZ, y0 = yt * TY, x0 = xt * TX;
    int tid = threadIdx.x;
    int px = tid & 7, py = (tid >> 3) & 3, pz = tid >> 5;

    float acc[C];
    #pragma unroll
    for (int oc = 0; oc < C; ++oc) acc[oc] = 0.f;

    for (int ic = 0; ic < C; ++ic) {
        __syncthreads();
        const float* xb = x + (size_t)(b * C + ic) * (XN * XN * XN);
        for (int i = tid; i < ITILE; i += 128) {
            int zt_ = i / (ITY * ITX);
            int rem = i - zt_ * (ITY * ITX);
            int yt_ = rem / ITX;
            int xt_ = rem - yt_ * ITX;
            int gz = 2 * z0 - 1 + zt_;
            int gy = 2 * y0 - 1 + yt_;
            int gx = 2 * x0 - 1 + xt_;
            float v = 0.f;
            if ((unsigned)gz < (unsigned)XN && (unsigned)gy < (unsigned)XN &&
                (unsigned)gx < (unsigned)XN)
                v = xb[gz * (XN * XN) + gy * XN + gx];
            tile[i] = v;
        }
        __syncthreads();
        const float* wic = w4 + ic * (64 * C);
        #pragma unroll
        for (int uz = 0; uz < 4; ++uz)
        #pragma unroll
        for (int uy = 0; uy < 4; ++uy) {
            int base = (2 * pz + uz) * (ITY * ITX) + (2 * py + uy) * ITX + 2 * px;
            float v[4];
            v[0] = tile[base + 0];
            v[1] = tile[base + 1];
            v[2] = tile[base + 2];
            v[3] = tile[base + 3];
            #pragma unroll
            for (int ux = 0; ux < 4; ++ux) {
                const float* wp = wic + (uz * 16 + uy * 4 + ux) * C;  // uniform -> s_load
                #pragma unroll
                for (int oc = 0; oc < C; ++oc)
                    acc[oc] = fmaf(v[ux], wp[oc], acc[oc]);
            }
        }
    }

    int sp = (z0 + pz) * (DN * DN) + (y0 + py) * DN + (x0 + px);
    float ds = 0.f;
    #pragma unroll
    for (int oc = 0; oc < C; ++oc) {
        float d = acc[oc] + bias[oc];
        ds += d;
        Dout[(size_t)(b * C + oc) * (DN * DN * DN) + sp] = d;
    }
    Dsum[b * (DN * DN * DN) + sp] = ds;
}

// ---- K2: 5^3 gaussian on (Dsum, P0*Dsum, P1*Dsum, P2*Dsum) -> filt + gridmean
__global__ __launch_bounds__(256) void k_gauss(const float* __restrict__ Dsum,
                                               const float* __restrict__ gaus_w,
                                               float* __restrict__ filt,
                                               float* __restrict__ outg) {
    int i = blockIdx.x * 256 + threadIdx.x;   // 2 * 32768
    if (i >= 2 * DN * DN * DN) return;
    int b  = i >> 15;
    int sp = i & 32767;
    int z = sp >> 10, y = (sp >> 5) & 31, xx = sp & 31;
    const float* Ds = Dsum + b * (DN * DN * DN);
    const float inv31 = 1.f / 31.f;
    float p = 0.f, a0 = 0.f, a1 = 0.f, a2 = 0.f;
    for (int tz = 0; tz < 5; ++tz) {
        int zz = z + tz - 2; if ((unsigned)zz >= (unsigned)DN) continue;
        for (int ty = 0; ty < 5; ++ty) {
            int yy = y + ty - 2; if ((unsigned)yy >= (unsigned)DN) continue;
            #pragma unroll
            for (int tx = 0; tx < 5; ++tx) {
                int xc = xx + tx - 2; if ((unsigned)xc >= (unsigned)DN) continue;
                float g = gaus_w[tz * 25 + ty * 5 + tx];  // gk replicated; [0,0,...]
                float v = g * Ds[zz * (DN * DN) + yy * DN + xc];
                p += v;
                a0 = fmaf(v, (float)zz * inv31, a0);
                a1 = fmaf(v, (float)yy * inv31, a1);
                a2 = fmaf(v, (float)xc * inv31, a2);
            }
        }
    }
    float denom = p + 1e-6f;
    float f0 = fminf(fmaxf(a0 / denom * 2.f - 1.f, -1.f), 1.f);
    float f1 = fminf(fmaxf(a1 / denom * 2.f - 1.f, -1.f), 1.f);
    float f2 = fminf(fmaxf(a2 / denom * 2.f - 1.f, -1.f), 1.f);
    int vol = DN * DN * DN;
    filt[(b * 3 + 0) * vol + sp] = f0;
    filt[(b * 3 + 1) * vol + sp] = f1;
    filt[(b * 3 + 2) * vol + sp] = f2;
    outg[(size_t)(b * vol + sp) * 3 + 0] = f0;
    outg[(size_t)(b * vol + sp) * 3 + 1] = f1;
    outg[(size_t)(b * vol + sp) * 3 + 2] = f2;
}

// ---- K3: trilinear grid sample (zeros padding, align_corners=False)
// filt axis 0 -> x (fastest dim of vol), axis 1 -> y (middle), axis 2 -> z (first)
__global__ __launch_bounds__(256) void k_sample(const float* __restrict__ x,
                                                const float* __restrict__ filt,
                                                float* __restrict__ y) {
    int bid = blockIdx.x;             // 2*32*32
    int wy = bid & 31; bid >>= 5;
    int z  = bid & 31; bid >>= 5;
    int b  = bid;
    int tid = threadIdx.x;
    int d  = tid & 31;                // fastest output dim
    int cg = tid >> 5;                // 8 groups x 4 channels
    int vol = DN * DN * DN;
    int sp = z * (DN * DN) + wy * DN + d;
    const float* fb = filt + b * 3 * vol;
    float g0 = fb[sp], g1 = fb[vol + sp], g2 = fb[2 * vol + sp];

    float ix = ((g0 + 1.0f) * (float)XN - 1.0f) * 0.5f;
    float iy = ((g1 + 1.0f) * (float)XN - 1.0f) * 0.5f;
    float iz = ((g2 + 1.0f) * (float)XN - 1.0f) * 0.5f;
    float x0f = floorf(ix), y0f = floorf(iy), z0f = floorf(iz);
    float wx = ix - x0f, wyf = iy - y0f, wz = iz - z0f;
    int x0 = (int)x0f, y0i = (int)y0f, z0 = (int)z0f;

    int offs[8];
    float wts[8];
    #pragma unroll
    for (int t = 0; t < 8; ++t) {
        int dz = t >> 2, dy = (t >> 1) & 1, dx = t & 1;
        int zc = z0 + dz, yc = y0i + dy, xc = x0 + dx;
        bool valid = (unsigned)zc < (unsigned)XN && (unsigned)yc < (unsigned)XN &&
                     (unsigned)xc < (unsigned)XN;
        int zcl = min(max(zc, 0), XN - 1);
        int ycl = min(max(yc, 0), XN - 1);
        int xcl = min(max(xc, 0), XN - 1);
        offs[t] = zcl * (XN * XN) + ycl * XN + xcl;
        float w = (dz ? wz : 1.f - wz) * (dy ? wyf : 1.f - wyf) * (dx ? wx : 1.f - wx);
        wts[t] = valid ? w : 0.f;
    }

    #pragma unroll
    for (int j = 0; j < 4; ++j) {
        int c = cg * 4 + j;
        const float* xb = x + (size_t)(b * C + c) * (XN * XN * XN);
        float acc = 0.f;
        #pragma unroll
        for (int t = 0; t < 8; ++t) acc = fmaf(wts[t], xb[offs[t]], acc);
        y[(size_t)(b * C + c) * vol + sp] = acc;
    }
}

extern "C" void kernel_launch(void* const* d_in, const int* in_sizes, int n_in,
                              void* d_out, int out_size, void* d_ws, size_t ws_size,
                              hipStream_t stream) {
    const float* x      = (const float*)d_in[0];   // (2,32,64,64,64)
    const float* conv_w = (const float*)d_in[1];   // (32,32,3,3,3)
    const float* conv_b = (const float*)d_in[2];   // (32,)
    const float* gaus_w = (const float*)d_in[3];   // (32,32,5,5,5) replicated

    float* out = (float*)d_out;
    const int vol = DN * DN * DN;                  // 32768
    float* y_out  = out;                           // 2*32*32768
    float* D_out  = out + (size_t)2 * C * vol;     // 2*32*32768
    float* g_out  = out + (size_t)4 * C * vol / 2 * 2; // = out + 2*2*C*vol? compute below

    // explicit offsets
    D_out = out + (size_t)2097152;
    g_out = out + (size_t)4194304;

    float* ws     = (float*)d_ws;
    float* Dsum   = ws;                 // 65536
    float* filt   = ws + 65536;         // 196608
    float* w4     = ws + 65536 + 196608; // 65536

    k_build_w4<<<dim3(256), dim3(256), 0, stream>>>(conv_w, w4);
    k_conv_pool<<<dim3(512), dim3(128), 0, stream>>>(x, w4, conv_b, D_out, Dsum);
    k_gauss<<<dim3(256), dim3(256), 0, stream>>>(Dsum, gaus_w, filt, g_out);
    k_sample<<<dim3(2048), dim3(256), 0, stream>>>(x, filt, y_out);
    (void)y_out; (void)in_sizes; (void)n_in; (void)out_size; (void)ws_size;
}

// Round 2
// 187.758 us; speedup vs baseline: 3.1207x; 3.1207x over previous
//
#include <hip/hip_runtime.h>

// ---------------------------------------------------------------------------
// Def_DownSampling, round 2: MFMA bf16 GEMM-conv for D + fused fp32 Dsum.
//  * gaus_w identical per (oc,ic) => gaussian path uses channel-summed field.
//  * conv3+avgpool folded to stride-2 4^3 conv (W4), exact algebra.
//  * D (direct output, thr 7.6e-2) via bf16 MFMA: err ~5e-3, safe.
//  * Grid path (ratio-amplified ~1e5): Dsum kept fp32 via fused VALU dot with
//    pre-summed weights wsum[k] on the SAME fp32 tap values (pre-bf16-cvt).
// Outputs: y (2,32,32,32,32) | D (2,32,32,32,32) | grid-mean (2,32,32,32,3)
// ---------------------------------------------------------------------------

#define XN 64
#define DN 32
#define C  32

typedef __attribute__((ext_vector_type(8))) short short8v;
typedef __attribute__((ext_vector_type(4))) float float4v;

static __device__ __forceinline__ short f2bf(float f) {
    union { float f; unsigned u; } v; v.f = f;
    unsigned r = (v.u + 0x7fffu + ((v.u >> 16) & 1u)) >> 16;   // RNE
    return (short)r;
}

// W4[ic][u][oc] = (1/8) sum_{s in {0,1}^3} conv_w[oc][ic][u-s]
static __device__ __forceinline__ float w4val(const float* __restrict__ conv_w,
                                              int ic, int u, int oc) {
    int uz = u >> 4, uy = (u >> 2) & 3, ux = u & 3;
    float s = 0.f;
    #pragma unroll
    for (int sz = 0; sz < 2; ++sz) {
        int tz = uz - sz; if (tz < 0 || tz > 2) continue;
        #pragma unroll
        for (int sy = 0; sy < 2; ++sy) {
            int ty = uy - sy; if (ty < 0 || ty > 2) continue;
            #pragma unroll
            for (int sx = 0; sx < 2; ++sx) {
                int tx = ux - sx; if (tx < 0 || tx > 2) continue;
                s += conv_w[(oc * C + ic) * 27 + tz * 9 + ty * 3 + tx];
            }
        }
    }
    return 0.125f * s;
}

// ---- K0: pack A-fragments (bf16) + wsum (fp32) + biassum
// wfrag index = ((step*2+f)*64 + lane)*8 + e ; value = W[oc=f*16+(lane&15)]
//               [k = step*32 + (lane>>4)*8 + e], W[oc][k] = W4[k>>6][k&63][oc]
__global__ __launch_bounds__(256) void k_prep(const float* __restrict__ conv_w,
                                              const float* __restrict__ conv_b,
                                              unsigned short* __restrict__ wfrag,
                                              float* __restrict__ wsum) {
    int i = blockIdx.x * 256 + threadIdx.x;     // 65536
    int e = i & 7;
    int l = (i >> 3) & 63;
    int sf = i >> 9;                            // step*2 + f
    int f = sf & 1, step = sf >> 1;
    int oc = f * 16 + (l & 15);
    int k = step * 32 + ((l >> 4) * 8 + e);
    float v = w4val(conv_w, k >> 6, k & 63, oc);
    wfrag[i] = (unsigned short)f2bf(v);

    if (i < 2048) {
        float s = 0.f;
        for (int o = 0; o < C; ++o) s += w4val(conv_w, i >> 6, i & 63, o);
        wsum[i] = s;
    }
    if (i == 0) {
        float s = 0.f;
        for (int o = 0; o < C; ++o) s += conv_b[o];
        wsum[2048] = s;
    }
}

// ---- K1: MFMA conv. Block = 256 thr = 4 waves; tile (z2,y2,x16) = 64 pos.
// Wave w: (wpz=w>>1, wpy=w&1), 16 positions x = xt*16 + (lane&15), all 32 oc.
#define TILEF (6 * 6 * 36)     // fp32 LDS tile, row stride 36 (b64-aligned)

static __device__ __forceinline__ void stage_load(float sv[5],
        const float* __restrict__ xp, int gz0, int gy0, int gx0, int tid) {
    #pragma unroll
    for (int it = 0; it < 5; ++it) {
        int i = tid + it * 256;
        float v = 0.f;
        if (i < 6 * 6 * 34) {
            int lx = i % 34; int r = i / 34; int ly = r % 6; int lz = r / 6;
            int gz = gz0 + lz, gy = gy0 + ly, gx = gx0 + lx;
            if ((unsigned)gz < XN && (unsigned)gy < XN && (unsigned)gx < XN)
                v = xp[(gz * XN + gy) * XN + gx];
        }
        sv[it] = v;
    }
}
static __device__ __forceinline__ void stage_write(float* __restrict__ dst,
        const float sv[5], int tid) {
    #pragma unroll
    for (int it = 0; it < 5; ++it) {
        int i = tid + it * 256;
        if (i < 6 * 6 * 34) {
            int lx = i % 34; int r = i / 34; int ly = r % 6; int lz = r / 6;
            dst[(lz * 6 + ly) * 36 + lx] = sv[it];
        }
    }
}

__global__ __launch_bounds__(256) void k_conv_mfma(
        const float* __restrict__ x, const unsigned short* __restrict__ wfrag,
        const float* __restrict__ wsum, const float* __restrict__ bias,
        float* __restrict__ Dout, float* __restrict__ Dsum) {
    __shared__ float tile[2][TILEF];
    int bid = blockIdx.x;
    int xt = bid & 1;
    int yt = (bid >> 1) & 15;
    int zt = (bid >> 5) & 15;
    int b  = bid >> 9;
    int tid = threadIdx.x;
    int w = tid >> 6, lane = tid & 63;
    int col = lane & 15, g = lane >> 4;
    int wpz = w >> 1, wpy = w & 1;
    int pz = zt * 2 + wpz, py = yt * 2 + wpy, px = xt * 16 + col;

    int gz0 = zt * 4 - 1, gy0 = yt * 4 - 1, gx0 = xt * 32 - 1;
    const float* xb_base = x + (size_t)b * C * (XN * XN * XN);

    // per-lane LDS read base (floats); h adds 432, row2 adds 36
    int base_g = ((2 * wpz + (g >> 1)) * 6 + 2 * wpy + (g & 1) * 2) * 36 + 2 * col;

    float4v acc0 = {0.f, 0.f, 0.f, 0.f};
    float4v acc1 = {0.f, 0.f, 0.f, 0.f};
    float dp = 0.f;

    {   // prologue: stage ic=0
        float sv[5];
        stage_load(sv, xb_base, gz0, gy0, gx0, tid);
        stage_write(tile[0], sv, tid);
    }

    for (int ic = 0; ic < C; ++ic) {
        __syncthreads();
        float sv[5];
        bool more = (ic + 1 < C);
        if (more)
            stage_load(sv, xb_base + (size_t)(ic + 1) * (XN * XN * XN),
                       gz0, gy0, gx0, tid);
        const float* t = tile[ic & 1];
        #pragma unroll
        for (int h = 0; h < 2; ++h) {
            int step = ic * 2 + h;
            int off0 = base_g + h * 432;
            float2 v01 = *(const float2*)&t[off0];
            float2 v23 = *(const float2*)&t[off0 + 2];
            float2 v45 = *(const float2*)&t[off0 + 36];
            float2 v67 = *(const float2*)&t[off0 + 38];
            float4v wlo = *(const float4v*)&wsum[step * 32 + g * 8];
            float4v whi = *(const float4v*)&wsum[step * 32 + g * 8 + 4];
            dp = fmaf(wlo.x, v01.x, dp); dp = fmaf(wlo.y, v01.y, dp);
            dp = fmaf(wlo.z, v23.x, dp); dp = fmaf(wlo.w, v23.y, dp);
            dp = fmaf(whi.x, v45.x, dp); dp = fmaf(whi.y, v45.y, dp);
            dp = fmaf(whi.z, v67.x, dp); dp = fmaf(whi.w, v67.y, dp);
            short8v bfr;
            bfr[0] = f2bf(v01.x); bfr[1] = f2bf(v01.y);
            bfr[2] = f2bf(v23.x); bfr[3] = f2bf(v23.y);
            bfr[4] = f2bf(v45.x); bfr[5] = f2bf(v45.y);
            bfr[6] = f2bf(v67.x); bfr[7] = f2bf(v67.y);
            short8v a0 = *(const short8v*)&wfrag[((size_t)(step * 2 + 0) * 64 + lane) * 8];
            short8v a1 = *(const short8v*)&wfrag[((size_t)(step * 2 + 1) * 64 + lane) * 8];
            acc0 = __builtin_amdgcn_mfma_f32_16x16x32_bf16(a0, bfr, acc0, 0, 0, 0);
            acc1 = __builtin_amdgcn_mfma_f32_16x16x32_bf16(a1, bfr, acc1, 0, 0, 0);
        }
        if (more) stage_write(tile[(ic + 1) & 1], sv, tid);
    }

    // Dsum: reduce partials across k-groups g (lanes l, l^16, l^32, l^48)
    dp += __shfl_xor(dp, 16, 64);
    dp += __shfl_xor(dp, 32, 64);

    int sp = pz * (DN * DN) + py * DN + px;
    float4v b0 = *(const float4v*)&bias[g * 4];
    float4v b1 = *(const float4v*)&bias[16 + g * 4];
    #pragma unroll
    for (int r = 0; r < 4; ++r) {
        int oc0 = g * 4 + r;           // D row = (lane>>4)*4 + reg, col = pos
        int oc1 = 16 + g * 4 + r;
        Dout[(size_t)(b * C + oc0) * (DN * DN * DN) + sp] = acc0[r] + b0[r];
        Dout[(size_t)(b * C + oc1) * (DN * DN * DN) + sp] = acc1[r] + b1[r];
    }
    if (g == 0)
        Dsum[b * (DN * DN * DN) + sp] = dp + wsum[2048];
}

// ---- K2: 5^3 gaussian on (Dsum, P*Dsum) -> filt + gridmean (unchanged)
__global__ __launch_bounds__(256) void k_gauss(const float* __restrict__ Dsum,
                                               const float* __restrict__ gaus_w,
                                               float* __restrict__ filt,
                                               float* __restrict__ outg) {
    int i = blockIdx.x * 256 + threadIdx.x;
    if (i >= 2 * DN * DN * DN) return;
    int b  = i >> 15;
    int sp = i & 32767;
    int z = sp >> 10, y = (sp >> 5) & 31, xx = sp & 31;
    const float* Ds = Dsum + b * (DN * DN * DN);
    const float inv31 = 1.f / 31.f;
    float p = 0.f, a0 = 0.f, a1 = 0.f, a2 = 0.f;
    for (int tz = 0; tz < 5; ++tz) {
        int zz = z + tz - 2; if ((unsigned)zz >= (unsigned)DN) continue;
        for (int ty = 0; ty < 5; ++ty) {
            int yy = y + ty - 2; if ((unsigned)yy >= (unsigned)DN) continue;
            #pragma unroll
            for (int tx = 0; tx < 5; ++tx) {
                int xc = xx + tx - 2; if ((unsigned)xc >= (unsigned)DN) continue;
                float gv = gaus_w[tz * 25 + ty * 5 + tx];
                float v = gv * Ds[zz * (DN * DN) + yy * DN + xc];
                p += v;
                a0 = fmaf(v, (float)zz * inv31, a0);
                a1 = fmaf(v, (float)yy * inv31, a1);
                a2 = fmaf(v, (float)xc * inv31, a2);
            }
        }
    }
    float denom = p + 1e-6f;
    float f0 = fminf(fmaxf(a0 / denom * 2.f - 1.f, -1.f), 1.f);
    float f1 = fminf(fmaxf(a1 / denom * 2.f - 1.f, -1.f), 1.f);
    float f2 = fminf(fmaxf(a2 / denom * 2.f - 1.f, -1.f), 1.f);
    int vol = DN * DN * DN;
    filt[(b * 3 + 0) * vol + sp] = f0;
    filt[(b * 3 + 1) * vol + sp] = f1;
    filt[(b * 3 + 2) * vol + sp] = f2;
    outg[(size_t)(b * vol + sp) * 3 + 0] = f0;
    outg[(size_t)(b * vol + sp) * 3 + 1] = f1;
    outg[(size_t)(b * vol + sp) * 3 + 2] = f2;
}

// ---- K3: trilinear grid sample (unchanged)
__global__ __launch_bounds__(256) void k_sample(const float* __restrict__ x,
                                                const float* __restrict__ filt,
                                                float* __restrict__ y) {
    int bid = blockIdx.x;
    int wy = bid & 31; bid >>= 5;
    int z  = bid & 31; bid >>= 5;
    int b  = bid;
    int tid = threadIdx.x;
    int d  = tid & 31;
    int cg = tid >> 5;
    int vol = DN * DN * DN;
    int sp = z * (DN * DN) + wy * DN + d;
    const float* fb = filt + b * 3 * vol;
    float g0 = fb[sp], g1 = fb[vol + sp], g2 = fb[2 * vol + sp];

    float ix = ((g0 + 1.0f) * (float)XN - 1.0f) * 0.5f;
    float iy = ((g1 + 1.0f) * (float)XN - 1.0f) * 0.5f;
    float iz = ((g2 + 1.0f) * (float)XN - 1.0f) * 0.5f;
    float x0f = floorf(ix), y0f = floorf(iy), z0f = floorf(iz);
    float wx = ix - x0f, wyf = iy - y0f, wz = iz - z0f;
    int x0 = (int)x0f, y0i = (int)y0f, z0 = (int)z0f;

    int offs[8];
    float wts[8];
    #pragma unroll
    for (int t = 0; t < 8; ++t) {
        int dz = t >> 2, dy = (t >> 1) & 1, dx = t & 1;
        int zc = z0 + dz, yc = y0i + dy, xc = x0 + dx;
        bool valid = (unsigned)zc < (unsigned)XN && (unsigned)yc < (unsigned)XN &&
                     (unsigned)xc < (unsigned)XN;
        int zcl = min(max(zc, 0), XN - 1);
        int ycl = min(max(yc, 0), XN - 1);
        int xcl = min(max(xc, 0), XN - 1);
        offs[t] = zcl * (XN * XN) + ycl * XN + xcl;
        float w = (dz ? wz : 1.f - wz) * (dy ? wyf : 1.f - wyf) * (dx ? wx : 1.f - wx);
        wts[t] = valid ? w : 0.f;
    }

    #pragma unroll
    for (int j = 0; j < 4; ++j) {
        int c = cg * 4 + j;
        const float* xb = x + (size_t)(b * C + c) * (XN * XN * XN);
        float acc = 0.f;
        #pragma unroll
        for (int t = 0; t < 8; ++t) acc = fmaf(wts[t], xb[offs[t]], acc);
        y[(size_t)(b * C + c) * vol + sp] = acc;
    }
}

extern "C" void kernel_launch(void* const* d_in, const int* in_sizes, int n_in,
                              void* d_out, int out_size, void* d_ws, size_t ws_size,
                              hipStream_t stream) {
    const float* x      = (const float*)d_in[0];
    const float* conv_w = (const float*)d_in[1];
    const float* conv_b = (const float*)d_in[2];
    const float* gaus_w = (const float*)d_in[3];

    float* out = (float*)d_out;
    float* y_out = out;
    float* D_out = out + (size_t)2097152;
    float* g_out = out + (size_t)4194304;

    float* ws   = (float*)d_ws;
    float* Dsum = ws;                         // 65536 f
    float* filt = ws + 65536;                 // 196608 f
    float* wsum = ws + 262144;                // 2049 f (+pad)
    unsigned short* wfrag = (unsigned short*)(ws + 264256);  // 65536 u16

    k_prep<<<dim3(256), dim3(256), 0, stream>>>(conv_w, conv_b, wfrag, wsum);
    k_conv_mfma<<<dim3(1024), dim3(256), 0, stream>>>(x, wfrag, wsum, conv_b,
                                                      D_out, Dsum);
    k_gauss<<<dim3(256), dim3(256), 0, stream>>>(Dsum, gaus_w, filt, g_out);
    k_sample<<<dim3(2048), dim3(256), 0, stream>>>(x, filt, y_out);
    (void)in_sizes; (void)n_in; (void)out_size; (void)ws_size;
}

// Round 3
// 167.851 us; speedup vs baseline: 3.4908x; 1.1186x over previous
//
#include <hip/hip_runtime.h>
#include <hip/hip_bf16.h>

// ---------------------------------------------------------------------------
// Def_DownSampling, round 3.
//  * gaus_w identical per (oc,ic) => gaussian path uses channel-summed field.
//  * conv3+avgpool folded to stride-2 4^3 conv (W4), exact algebra.
//  * D via bf16 MFMA; Dsum kept fp32 (fused VALU dot) for the grid path.
//  * R3: k_sample 3D-tiled for L2 locality + XCD swizzle; conv staging math
//    hoisted out of ic-loop + cvt_pk bf16 conversion.
// Outputs: y (2,32,32,32,32) | D (2,32,32,32,32) | grid-mean (2,32,32,32,3)
// ---------------------------------------------------------------------------

#define XN 64
#define DN 32
#define C  32

typedef __attribute__((ext_vector_type(8))) short short8v;
typedef __attribute__((ext_vector_type(4))) float float4v;

static __device__ __forceinline__ short f2bf(float f) {
    union { float f; unsigned u; } v; v.f = f;
    unsigned r = (v.u + 0x7fffu + ((v.u >> 16) & 1u)) >> 16;   // RNE
    return (short)r;
}

static __device__ __forceinline__ unsigned pk2(float a, float b) {
    __hip_bfloat162 h = __float22bfloat162_rn(float2{a, b});
    union { __hip_bfloat162 h2; unsigned u; } cv; cv.h2 = h;
    return cv.u;
}

// W4[ic][u][oc] = (1/8) sum_{s in {0,1}^3} conv_w[oc][ic][u-s]
static __device__ __forceinline__ float w4val(const float* __restrict__ conv_w,
                                              int ic, int u, int oc) {
    int uz = u >> 4, uy = (u >> 2) & 3, ux = u & 3;
    float s = 0.f;
    #pragma unroll
    for (int sz = 0; sz < 2; ++sz) {
        int tz = uz - sz; if (tz < 0 || tz > 2) continue;
        #pragma unroll
        for (int sy = 0; sy < 2; ++sy) {
            int ty = uy - sy; if (ty < 0 || ty > 2) continue;
            #pragma unroll
            for (int sx = 0; sx < 2; ++sx) {
                int tx = ux - sx; if (tx < 0 || tx > 2) continue;
                s += conv_w[(oc * C + ic) * 27 + tz * 9 + ty * 3 + tx];
            }
        }
    }
    return 0.125f * s;
}

// ---- K0: pack A-fragments (bf16) + wsum (fp32) + biassum
__global__ __launch_bounds__(256) void k_prep(const float* __restrict__ conv_w,
                                              const float* __restrict__ conv_b,
                                              unsigned short* __restrict__ wfrag,
                                              float* __restrict__ wsum) {
    int i = blockIdx.x * 256 + threadIdx.x;     // 65536
    int e = i & 7;
    int l = (i >> 3) & 63;
    int sf = i >> 9;
    int f = sf & 1, step = sf >> 1;
    int oc = f * 16 + (l & 15);
    int k = step * 32 + ((l >> 4) * 8 + e);
    float v = w4val(conv_w, k >> 6, k & 63, oc);
    wfrag[i] = (unsigned short)f2bf(v);

    if (i < 2048) {
        float s = 0.f;
        for (int o = 0; o < C; ++o) s += w4val(conv_w, i >> 6, i & 63, o);
        wsum[i] = s;
    }
    if (i == 0) {
        float s = 0.f;
        for (int o = 0; o < C; ++o) s += conv_b[o];
        wsum[2048] = s;
    }
}

// ---- K1: MFMA conv. 256 thr = 4 waves; tile (z2,y2,x16)=64 pos, all 32 oc.
#define TILEF (6 * 6 * 36)
#define NSTG  (6 * 6 * 34)     // 1224 staged floats

__global__ __launch_bounds__(256) void k_conv_mfma(
        const float* __restrict__ x, const unsigned short* __restrict__ wfrag,
        const float* __restrict__ wsum, const float* __restrict__ bias,
        float* __restrict__ Dout, float* __restrict__ Dsum) {
    __shared__ float tile[2][TILEF];
    int bid = blockIdx.x;
    int wid = (bid & 7) * 128 + (bid >> 3);     // XCD-chunked swizzle (1024%8==0)
    int xt = wid & 1;
    int yt = (wid >> 1) & 15;
    int zt = (wid >> 5) & 15;
    int b  = wid >> 9;
    int tid = threadIdx.x;
    int w = tid >> 6, lane = tid & 63;
    int col = lane & 15, g = lane >> 4;
    int wpz = w >> 1, wpy = w & 1;
    int pz = zt * 2 + wpz, py = yt * 2 + wpy, px = xt * 16 + col;

    int gz0 = zt * 4 - 1, gy0 = yt * 4 - 1, gx0 = xt * 32 - 1;
    const float* xb_base = x + (size_t)b * C * (XN * XN * XN);

    // hoisted (ic-invariant) staging index math
    int  soff[5], sdst[5];
    bool sval[5], swr[5];
    #pragma unroll
    for (int it = 0; it < 5; ++it) {
        int i = tid + it * 256;
        int lx = i % 34; int r = i / 34; int ly = r % 6; int lz = r / 6;
        int gz = gz0 + lz, gy = gy0 + ly, gx = gx0 + lx;
        bool inr = i < NSTG;
        swr[it]  = inr;
        sval[it] = inr && (unsigned)gz < XN && (unsigned)gy < XN && (unsigned)gx < XN;
        soff[it] = ((gz & 63) * XN + (gy & 63)) * XN + (gx & 63);
        sdst[it] = inr ? (lz * 6 + ly) * 36 + lx : 0;
    }

    int base_g = ((2 * wpz + (g >> 1)) * 6 + 2 * wpy + (g & 1) * 2) * 36 + 2 * col;

    float4v acc0 = {0.f, 0.f, 0.f, 0.f};
    float4v acc1 = {0.f, 0.f, 0.f, 0.f};
    float dp = 0.f;

    {   // prologue: stage ic=0
        float sv[5];
        #pragma unroll
        for (int it = 0; it < 5; ++it) sv[it] = sval[it] ? xb_base[soff[it]] : 0.f;
        #pragma unroll
        for (int it = 0; it < 5; ++it) if (swr[it]) tile[0][sdst[it]] = sv[it];
    }

    for (int ic = 0; ic < C; ++ic) {
        __syncthreads();
        float sv[5];
        bool more = (ic + 1 < C);
        if (more) {
            const float* xp = xb_base + (size_t)(ic + 1) * (XN * XN * XN);
            #pragma unroll
            for (int it = 0; it < 5; ++it) sv[it] = sval[it] ? xp[soff[it]] : 0.f;
        }
        const float* t = tile[ic & 1];
        #pragma unroll
        for (int h = 0; h < 2; ++h) {
            int step = ic * 2 + h;
            int off0 = base_g + h * 432;
            float2 v01 = *(const float2*)&t[off0];
            float2 v23 = *(const float2*)&t[off0 + 2];
            float2 v45 = *(const float2*)&t[off0 + 36];
            float2 v67 = *(const float2*)&t[off0 + 38];
            float4v wlo = *(const float4v*)&wsum[step * 32 + g * 8];
            float4v whi = *(const float4v*)&wsum[step * 32 + g * 8 + 4];
            dp = fmaf(wlo.x, v01.x, dp); dp = fmaf(wlo.y, v01.y, dp);
            dp = fmaf(wlo.z, v23.x, dp); dp = fmaf(wlo.w, v23.y, dp);
            dp = fmaf(whi.x, v45.x, dp); dp = fmaf(whi.y, v45.y, dp);
            dp = fmaf(whi.z, v67.x, dp); dp = fmaf(whi.w, v67.y, dp);
            union { short8v s; unsigned u[4]; } B;
            B.u[0] = pk2(v01.x, v01.y);
            B.u[1] = pk2(v23.x, v23.y);
            B.u[2] = pk2(v45.x, v45.y);
            B.u[3] = pk2(v67.x, v67.y);
            short8v a0 = *(const short8v*)&wfrag[((size_t)(step * 2 + 0) * 64 + lane) * 8];
            short8v a1 = *(const short8v*)&wfrag[((size_t)(step * 2 + 1) * 64 + lane) * 8];
            acc0 = __builtin_amdgcn_mfma_f32_16x16x32_bf16(a0, B.s, acc0, 0, 0, 0);
            acc1 = __builtin_amdgcn_mfma_f32_16x16x32_bf16(a1, B.s, acc1, 0, 0, 0);
        }
        if (more) {
            #pragma unroll
            for (int it = 0; it < 5; ++it)
                if (swr[it]) tile[(ic + 1) & 1][sdst[it]] = sv[it];
        }
    }

    dp += __shfl_xor(dp, 16, 64);
    dp += __shfl_xor(dp, 32, 64);

    int sp = pz * (DN * DN) + py * DN + px;
    float4v b0 = *(const float4v*)&bias[g * 4];
    float4v b1 = *(const float4v*)&bias[16 + g * 4];
    #pragma unroll
    for (int r = 0; r < 4; ++r) {
        int oc0 = g * 4 + r;
        int oc1 = 16 + g * 4 + r;
        Dout[(size_t)(b * C + oc0) * (DN * DN * DN) + sp] = acc0[r] + b0[r];
        Dout[(size_t)(b * C + oc1) * (DN * DN * DN) + sp] = acc1[r] + b1[r];
    }
    if (g == 0)
        Dsum[b * (DN * DN * DN) + sp] = dp + wsum[2048];
}

// ---- K2: 5^3 gaussian on (Dsum, P*Dsum) -> filt + gridmean
__global__ __launch_bounds__(256) void k_gauss(const float* __restrict__ Dsum,
                                               const float* __restrict__ gaus_w,
                                               float* __restrict__ filt,
                                               float* __restrict__ outg) {
    int i = blockIdx.x * 256 + threadIdx.x;
    if (i >= 2 * DN * DN * DN) return;
    int b  = i >> 15;
    int sp = i & 32767;
    int z = sp >> 10, y = (sp >> 5) & 31, xx = sp & 31;
    const float* Ds = Dsum + b * (DN * DN * DN);
    const float inv31 = 1.f / 31.f;
    float p = 0.f, a0 = 0.f, a1 = 0.f, a2 = 0.f;
    for (int tz = 0; tz < 5; ++tz) {
        int zz = z + tz - 2; if ((unsigned)zz >= (unsigned)DN) continue;
        for (int ty = 0; ty < 5; ++ty) {
            int yy = y + ty - 2; if ((unsigned)yy >= (unsigned)DN) continue;
            #pragma unroll
            for (int tx = 0; tx < 5; ++tx) {
                int xc = xx + tx - 2; if ((unsigned)xc >= (unsigned)DN) continue;
                float gv = gaus_w[tz * 25 + ty * 5 + tx];
                float v = gv * Ds[zz * (DN * DN) + yy * DN + xc];
                p += v;
                a0 = fmaf(v, (float)zz * inv31, a0);
                a1 = fmaf(v, (float)yy * inv31, a1);
                a2 = fmaf(v, (float)xc * inv31, a2);
            }
        }
    }
    float denom = p + 1e-6f;
    float f0 = fminf(fmaxf(a0 / denom * 2.f - 1.f, -1.f), 1.f);
    float f1 = fminf(fmaxf(a1 / denom * 2.f - 1.f, -1.f), 1.f);
    float f2 = fminf(fmaxf(a2 / denom * 2.f - 1.f, -1.f), 1.f);
    int vol = DN * DN * DN;
    filt[(b * 3 + 0) * vol + sp] = f0;
    filt[(b * 3 + 1) * vol + sp] = f1;
    filt[(b * 3 + 2) * vol + sp] = f2;
    outg[(size_t)(b * vol + sp) * 3 + 0] = f0;
    outg[(size_t)(b * vol + sp) * 3 + 1] = f1;
    outg[(size_t)(b * vol + sp) * 3 + 2] = f2;
}

// ---- K3: trilinear grid sample, 3D-tiled.
// Block: tile (4z x 4y x 16x) positions x 8 channels. 1024 blocks, 256 thr.
__global__ __launch_bounds__(256) void k_sample(const float* __restrict__ x,
                                                const float* __restrict__ filt,
                                                float* __restrict__ y) {
    int bid = blockIdx.x;
    int wid = (bid & 7) * 128 + (bid >> 3);     // XCD-chunked swizzle (1024%8==0)
    int cgrp = wid & 3;
    int xt = (wid >> 2) & 1;
    int yt = (wid >> 3) & 7;
    int zt = (wid >> 6) & 7;
    int b  = wid >> 9;
    int tid = threadIdx.x;
    int px = tid & 15, py = (tid >> 4) & 3, pz = tid >> 6;
    int vol = DN * DN * DN;
    int sp = ((zt * 4 + pz) * DN + yt * 4 + py) * DN + xt * 16 + px;
    const float* fb = filt + b * 3 * vol;
    float g0 = fb[sp], g1 = fb[vol + sp], g2 = fb[2 * vol + sp];

    float ix = ((g0 + 1.0f) * (float)XN - 1.0f) * 0.5f;
    float iy = ((g1 + 1.0f) * (float)XN - 1.0f) * 0.5f;
    float iz = ((g2 + 1.0f) * (float)XN - 1.0f) * 0.5f;
    float x0f = floorf(ix), y0f = floorf(iy), z0f = floorf(iz);
    float wx = ix - x0f, wyf = iy - y0f, wz = iz - z0f;
    int x0 = (int)x0f, y0i = (int)y0f, z0 = (int)z0f;

    int offs[8];
    float wts[8];
    #pragma unroll
    for (int t = 0; t < 8; ++t) {
        int dz = t >> 2, dy = (t >> 1) & 1, dx = t & 1;
        int zc = z0 + dz, yc = y0i + dy, xc = x0 + dx;
        bool valid = (unsigned)zc < (unsigned)XN && (unsigned)yc < (unsigned)XN &&
                     (unsigned)xc < (unsigned)XN;
        int zcl = min(max(zc, 0), XN - 1);
        int ycl = min(max(yc, 0), XN - 1);
        int xcl = min(max(xc, 0), XN - 1);
        offs[t] = zcl * (XN * XN) + ycl * XN + xcl;
        float w = (dz ? wz : 1.f - wz) * (dy ? wyf : 1.f - wyf) * (dx ? wx : 1.f - wx);
        wts[t] = valid ? w : 0.f;
    }

    #pragma unroll
    for (int j = 0; j < 8; ++j) {
        int c = cgrp * 8 + j;
        const float* xb = x + (size_t)(b * C + c) * (XN * XN * XN);
        float acc = 0.f;
        #pragma unroll
        for (int t = 0; t < 8; ++t) acc = fmaf(wts[t], xb[offs[t]], acc);
        y[(size_t)(b * C + c) * vol + sp] = acc;
    }
}

extern "C" void kernel_launch(void* const* d_in, const int* in_sizes, int n_in,
                              void* d_out, int out_size, void* d_ws, size_t ws_size,
                              hipStream_t stream) {
    const float* x      = (const float*)d_in[0];
    const float* conv_w = (const float*)d_in[1];
    const float* conv_b = (const float*)d_in[2];
    const float* gaus_w = (const float*)d_in[3];

    float* out = (float*)d_out;
    float* y_out = out;
    float* D_out = out + (size_t)2097152;
    float* g_out = out + (size_t)4194304;

    float* ws   = (float*)d_ws;
    float* Dsum = ws;                         // 65536 f
    float* filt = ws + 65536;                 // 196608 f
    float* wsum = ws + 262144;                // 2049 f (+pad)
    unsigned short* wfrag = (unsigned short*)(ws + 264256);  // 65536 u16

    k_prep<<<dim3(256), dim3(256), 0, stream>>>(conv_w, conv_b, wfrag, wsum);
    k_conv_mfma<<<dim3(1024), dim3(256), 0, stream>>>(x, wfrag, wsum, conv_b,
                                                      D_out, Dsum);
    k_gauss<<<dim3(256), dim3(256), 0, stream>>>(Dsum, gaus_w, filt, g_out);
    k_sample<<<dim3(1024), dim3(256), 0, stream>>>(x, filt, y_out);
    (void)in_sizes; (void)n_in; (void)out_size; (void)ws_size;
}

// Round 4
// 135.531 us; speedup vs baseline: 4.3232x; 1.2385x over previous
//
#include <hip/hip_runtime.h>
#include <hip/hip_bf16.h>

// ---------------------------------------------------------------------------
// Def_DownSampling, round 4.
//  * gaus_w identical per (oc,ic) => gaussian path uses channel-summed field.
//  * conv3+avgpool folded to stride-2 4^3 conv (W4), exact algebra.
//  * D via bf16 MFMA; Dsum kept fp32 (fused VALU dot) for the grid path.
//  * R4: k_sample reworked for MLP (reg-batched taps) + per-XCD channel-chunk;
//    conv staging split issue-early/write-late across iterations (T14);
//    k_gauss LDS-staged.
// Outputs: y (2,32,32,32,32) | D (2,32,32,32,32) | grid-mean (2,32,32,32,3)
// ---------------------------------------------------------------------------

#define XN 64
#define DN 32
#define C  32
#define XVOL (XN * XN * XN)   // 262144
#define DVOL (DN * DN * DN)   // 32768

typedef __attribute__((ext_vector_type(8))) short short8v;
typedef __attribute__((ext_vector_type(4))) float float4v;

static __device__ __forceinline__ short f2bf(float f) {
    union { float f; unsigned u; } v; v.f = f;
    unsigned r = (v.u + 0x7fffu + ((v.u >> 16) & 1u)) >> 16;   // RNE
    return (short)r;
}

static __device__ __forceinline__ unsigned pk2(float a, float b) {
    __hip_bfloat162 h = __float22bfloat162_rn(float2{a, b});
    union { __hip_bfloat162 h2; unsigned u; } cv; cv.h2 = h;
    return cv.u;
}

// W4[ic][u][oc] = (1/8) sum_{s in {0,1}^3} conv_w[oc][ic][u-s]
static __device__ __forceinline__ float w4val(const float* __restrict__ conv_w,
                                              int ic, int u, int oc) {
    int uz = u >> 4, uy = (u >> 2) & 3, ux = u & 3;
    float s = 0.f;
    #pragma unroll
    for (int sz = 0; sz < 2; ++sz) {
        int tz = uz - sz; if (tz < 0 || tz > 2) continue;
        #pragma unroll
        for (int sy = 0; sy < 2; ++sy) {
            int ty = uy - sy; if (ty < 0 || ty > 2) continue;
            #pragma unroll
            for (int sx = 0; sx < 2; ++sx) {
                int tx = ux - sx; if (tx < 0 || tx > 2) continue;
                s += conv_w[(oc * C + ic) * 27 + tz * 9 + ty * 3 + tx];
            }
        }
    }
    return 0.125f * s;
}

// ---- K0: pack A-fragments (bf16) + wsum (fp32) + biassum
__global__ __launch_bounds__(256) void k_prep(const float* __restrict__ conv_w,
                                              const float* __restrict__ conv_b,
                                              unsigned short* __restrict__ wfrag,
                                              float* __restrict__ wsum) {
    int i = blockIdx.x * 256 + threadIdx.x;     // 65536
    int e = i & 7;
    int l = (i >> 3) & 63;
    int sf = i >> 9;
    int f = sf & 1, step = sf >> 1;
    int oc = f * 16 + (l & 15);
    int k = step * 32 + ((l >> 4) * 8 + e);
    float v = w4val(conv_w, k >> 6, k & 63, oc);
    wfrag[i] = (unsigned short)f2bf(v);

    if (i < 2048) {
        float s = 0.f;
        for (int o = 0; o < C; ++o) s += w4val(conv_w, i >> 6, i & 63, o);
        wsum[i] = s;
    }
    if (i == 0) {
        float s = 0.f;
        for (int o = 0; o < C; ++o) s += conv_b[o];
        wsum[2048] = s;
    }
}

// ---- K1: MFMA conv. 256 thr = 4 waves; tile (z2,y2,x16)=64 pos, all 32 oc.
#define TILEF (6 * 6 * 36)
#define NSTG  (6 * 6 * 34)     // 1224 staged floats

__global__ __launch_bounds__(256) void k_conv_mfma(
        const float* __restrict__ x, const unsigned short* __restrict__ wfrag,
        const float* __restrict__ wsum, const float* __restrict__ bias,
        float* __restrict__ Dout, float* __restrict__ Dsum) {
    __shared__ float tile[2][TILEF];
    int bid = blockIdx.x;
    int wid = (bid & 7) * 128 + (bid >> 3);     // XCD-chunked swizzle (1024%8==0)
    int xt = wid & 1;
    int yt = (wid >> 1) & 15;
    int zt = (wid >> 5) & 15;
    int b  = wid >> 9;
    int tid = threadIdx.x;
    int w = tid >> 6, lane = tid & 63;
    int col = lane & 15, g = lane >> 4;
    int wpz = w >> 1, wpy = w & 1;
    int pz = zt * 2 + wpz, py = yt * 2 + wpy, px = xt * 16 + col;

    int gz0 = zt * 4 - 1, gy0 = yt * 4 - 1, gx0 = xt * 32 - 1;
    const float* xb_base = x + (size_t)b * C * XVOL;

    // hoisted (ic-invariant) staging index math
    int  soff[5], sdst[5];
    bool sval[5], swr[5];
    #pragma unroll
    for (int it = 0; it < 5; ++it) {
        int i = tid + it * 256;
        int lx = i % 34; int r = i / 34; int ly = r % 6; int lz = r / 6;
        int gz = gz0 + lz, gy = gy0 + ly, gx = gx0 + lx;
        bool inr = i < NSTG;
        swr[it]  = inr;
        sval[it] = inr && (unsigned)gz < XN && (unsigned)gy < XN && (unsigned)gx < XN;
        soff[it] = ((gz & 63) * XN + (gy & 63)) * XN + (gx & 63);
        sdst[it] = inr ? (lz * 6 + ly) * 36 + lx : 0;
    }

    int base_g = ((2 * wpz + (g >> 1)) * 6 + 2 * wpy + (g & 1) * 2) * 36 + 2 * col;

    float4v acc0 = {0.f, 0.f, 0.f, 0.f};
    float4v acc1 = {0.f, 0.f, 0.f, 0.f};
    float dp = 0.f;

    {   // prologue: stage ic=0 (one exposed latency), preload ic=1 to regs
        float sv[5];
        #pragma unroll
        for (int it = 0; it < 5; ++it) sv[it] = sval[it] ? xb_base[soff[it]] : 0.f;
        #pragma unroll
        for (int it = 0; it < 5; ++it) if (swr[it]) tile[0][sdst[it]] = sv[it];
    }
    float svB[5];
    {
        const float* xp = xb_base + XVOL;
        #pragma unroll
        for (int it = 0; it < 5; ++it) svB[it] = sval[it] ? xp[soff[it]] : 0.f;
    }

    for (int ic = 0; ic < C; ++ic) {
        __syncthreads();
        // write-late: svB holds data for ic+1, loaded one iteration ago
        if (ic + 1 < C) {
            float* dst = tile[(ic + 1) & 1];
            #pragma unroll
            for (int it = 0; it < 5; ++it) if (swr[it]) dst[sdst[it]] = svB[it];
        }
        // issue-early: loads for ic+2 (land during this iter's compute + next barrier)
        float svA[5];
        if (ic + 2 < C) {
            const float* xp = xb_base + (size_t)(ic + 2) * XVOL;
            #pragma unroll
            for (int it = 0; it < 5; ++it) svA[it] = sval[it] ? xp[soff[it]] : 0.f;
        }
        const float* t = tile[ic & 1];
        #pragma unroll
        for (int h = 0; h < 2; ++h) {
            int step = ic * 2 + h;
            int off0 = base_g + h * 432;
            float2 v01 = *(const float2*)&t[off0];
            float2 v23 = *(const float2*)&t[off0 + 2];
            float2 v45 = *(const float2*)&t[off0 + 36];
            float2 v67 = *(const float2*)&t[off0 + 38];
            float4v wlo = *(const float4v*)&wsum[step * 32 + g * 8];
            float4v whi = *(const float4v*)&wsum[step * 32 + g * 8 + 4];
            dp = fmaf(wlo.x, v01.x, dp); dp = fmaf(wlo.y, v01.y, dp);
            dp = fmaf(wlo.z, v23.x, dp); dp = fmaf(wlo.w, v23.y, dp);
            dp = fmaf(whi.x, v45.x, dp); dp = fmaf(whi.y, v45.y, dp);
            dp = fmaf(whi.z, v67.x, dp); dp = fmaf(whi.w, v67.y, dp);
            union { short8v s; unsigned u[4]; } B;
            B.u[0] = pk2(v01.x, v01.y);
            B.u[1] = pk2(v23.x, v23.y);
            B.u[2] = pk2(v45.x, v45.y);
            B.u[3] = pk2(v67.x, v67.y);
            short8v a0 = *(const short8v*)&wfrag[((size_t)(step * 2 + 0) * 64 + lane) * 8];
            short8v a1 = *(const short8v*)&wfrag[((size_t)(step * 2 + 1) * 64 + lane) * 8];
            acc0 = __builtin_amdgcn_mfma_f32_16x16x32_bf16(a0, B.s, acc0, 0, 0, 0);
            acc1 = __builtin_amdgcn_mfma_f32_16x16x32_bf16(a1, B.s, acc1, 0, 0, 0);
        }
        if (ic + 2 < C) {
            #pragma unroll
            for (int it = 0; it < 5; ++it) svB[it] = svA[it];
        }
    }

    dp += __shfl_xor(dp, 16, 64);
    dp += __shfl_xor(dp, 32, 64);

    int sp = pz * (DN * DN) + py * DN + px;
    float4v b0 = *(const float4v*)&bias[g * 4];
    float4v b1 = *(const float4v*)&bias[16 + g * 4];
    #pragma unroll
    for (int r = 0; r < 4; ++r) {
        int oc0 = g * 4 + r;
        int oc1 = 16 + g * 4 + r;
        Dout[(size_t)(b * C + oc0) * DVOL + sp] = acc0[r] + b0[r];
        Dout[(size_t)(b * C + oc1) * DVOL + sp] = acc1[r] + b1[r];
    }
    if (g == 0)
        Dsum[b * DVOL + sp] = dp + wsum[2048];
}

// ---- K2: 5^3 gaussian, LDS-staged. Block = (4z x 8y x 8x), 256 blocks.
__global__ __launch_bounds__(256) void k_gauss(const float* __restrict__ Dsum,
                                               const float* __restrict__ gaus_w,
                                               float* __restrict__ filt,
                                               float* __restrict__ outg) {
    __shared__ float tg[8 * 12 * 12];   // 1152
    __shared__ float gk[125];
    int bid = blockIdx.x;
    int xt = bid & 3, yt = (bid >> 2) & 3, zt = (bid >> 4) & 7, b = bid >> 7;
    int tid = threadIdx.x;
    if (tid < 125) gk[tid] = gaus_w[tid];   // replicated kernel: [0][0] slice
    const float* Ds = Dsum + b * DVOL;
    for (int i = tid; i < 1152; i += 256) {
        int lx = i % 12; int r = i / 12; int ly = r % 12; int lz = r / 12;
        int gz = zt * 4 - 2 + lz, gy = yt * 8 - 2 + ly, gx = xt * 8 - 2 + lx;
        float v = 0.f;
        if ((unsigned)gz < DN && (unsigned)gy < DN && (unsigned)gx < DN)
            v = Ds[(gz * DN + gy) * DN + gx];
        tg[i] = v;
    }
    __syncthreads();
    int px = tid & 7, py = (tid >> 3) & 7, pz = tid >> 6;
    const float inv31 = 1.f / 31.f;
    float zb = (float)(zt * 4 + pz - 2);
    float yb = (float)(yt * 8 + py - 2);
    float xb = (float)(xt * 8 + px - 2);
    float p = 0.f, a0 = 0.f, a1 = 0.f, a2 = 0.f;
    for (int tz = 0; tz < 5; ++tz)
    for (int ty = 0; ty < 5; ++ty) {
        int base = ((pz + tz) * 12 + py + ty) * 12 + px;
        #pragma unroll
        for (int tx = 0; tx < 5; ++tx) {
            float g = gk[tz * 25 + ty * 5 + tx];
            float v = g * tg[base + tx];
            p += v;
            a0 = fmaf(v, (zb + (float)tz) * inv31, a0);
            a1 = fmaf(v, (yb + (float)ty) * inv31, a1);
            a2 = fmaf(v, (xb + (float)tx) * inv31, a2);
        }
    }
    float denom = p + 1e-6f;
    float f0 = fminf(fmaxf(a0 / denom * 2.f - 1.f, -1.f), 1.f);
    float f1 = fminf(fmaxf(a1 / denom * 2.f - 1.f, -1.f), 1.f);
    float f2 = fminf(fmaxf(a2 / denom * 2.f - 1.f, -1.f), 1.f);
    int sp = ((zt * 4 + pz) * DN + yt * 8 + py) * DN + xt * 8 + px;
    filt[(b * 3 + 0) * DVOL + sp] = f0;
    filt[(b * 3 + 1) * DVOL + sp] = f1;
    filt[(b * 3 + 2) * DVOL + sp] = f2;
    outg[(size_t)(b * DVOL + sp) * 3 + 0] = f0;
    outg[(size_t)(b * DVOL + sp) * 3 + 1] = f1;
    outg[(size_t)(b * DVOL + sp) * 3 + 2] = f2;
}

// ---- K3: trilinear grid sample. 2048 blocks x 128 thr; tile (2z,4y,16x),
// 8 channels per block. XCD chunk = one (b, channel-group), z-major.
__global__ __launch_bounds__(128, 4) void k_sample(const float* __restrict__ x,
                                                   const float* __restrict__ filt,
                                                   float* __restrict__ y) {
    int bid = blockIdx.x;
    int wid = (bid & 7) * 256 + (bid >> 3);   // 2048%8==0, bijective chunk
    int xt = wid & 1;
    int yt = (wid >> 1) & 7;
    int zt = (wid >> 4) & 15;
    int cgrp = (wid >> 8) & 3;
    int b  = wid >> 10;
    int tid = threadIdx.x;
    int px = tid & 15, py = (tid >> 4) & 3, pz = tid >> 6;
    int sp = ((zt * 2 + pz) * DN + yt * 4 + py) * DN + xt * 16 + px;
    const float* fb = filt + b * 3 * DVOL;
    float g0 = fb[sp], g1 = fb[DVOL + sp], g2 = fb[2 * DVOL + sp];

    float ix = ((g0 + 1.0f) * (float)XN - 1.0f) * 0.5f;
    float iy = ((g1 + 1.0f) * (float)XN - 1.0f) * 0.5f;
    float iz = ((g2 + 1.0f) * (float)XN - 1.0f) * 0.5f;
    float x0f = floorf(ix), y0f = floorf(iy), z0f = floorf(iz);
    float wx = ix - x0f, wyf = iy - y0f, wz = iz - z0f;
    int x0 = (int)x0f, y0i = (int)y0f, z0 = (int)z0f;

    int offs[8];
    float wts[8];
    #pragma unroll
    for (int t = 0; t < 8; ++t) {
        int dz = t >> 2, dy = (t >> 1) & 1, dx = t & 1;
        int zc = z0 + dz, yc = y0i + dy, xc = x0 + dx;
        bool valid = (unsigned)zc < (unsigned)XN && (unsigned)yc < (unsigned)XN &&
                     (unsigned)xc < (unsigned)XN;
        int zcl = min(max(zc, 0), XN - 1);
        int ycl = min(max(yc, 0), XN - 1);
        int xcl = min(max(xc, 0), XN - 1);
        offs[t] = zcl * (XN * XN) + ycl * XN + xcl;
        float w = (dz ? wz : 1.f - wz) * (dy ? wyf : 1.f - wyf) * (dx ? wx : 1.f - wx);
        wts[t] = valid ? w : 0.f;
    }

    const float* xc0 = x + (size_t)(b * C + cgrp * 8) * XVOL;
    #pragma unroll
    for (int g = 0; g < 2; ++g) {
        float t[4][8];                       // 32 loads in flight
        #pragma unroll
        for (int j = 0; j < 4; ++j) {
            const float* xb = xc0 + (size_t)(g * 4 + j) * XVOL;
            #pragma unroll
            for (int k = 0; k < 8; ++k) t[j][k] = xb[offs[k]];
        }
        #pragma unroll
        for (int j = 0; j < 4; ++j) {
            float acc = 0.f;
            #pragma unroll
            for (int k = 0; k < 8; ++k) acc = fmaf(wts[k], t[j][k], acc);
            y[(size_t)(b * C + cgrp * 8 + g * 4 + j) * DVOL + sp] = acc;
        }
    }
}

extern "C" void kernel_launch(void* const* d_in, const int* in_sizes, int n_in,
                              void* d_out, int out_size, void* d_ws, size_t ws_size,
                              hipStream_t stream) {
    const float* x      = (const float*)d_in[0];
    const float* conv_w = (const float*)d_in[1];
    const float* conv_b = (const float*)d_in[2];
    const float* gaus_w = (const float*)d_in[3];

    float* out = (float*)d_out;
    float* y_out = out;
    float* D_out = out + (size_t)2097152;
    float* g_out = out + (size_t)4194304;

    float* ws   = (float*)d_ws;
    float* Dsum = ws;                         // 65536 f
    float* filt = ws + 65536;                 // 196608 f
    float* wsum = ws + 262144;                // 2049 f (+pad)
    unsigned short* wfrag = (unsigned short*)(ws + 264256);  // 65536 u16

    k_prep<<<dim3(256), dim3(256), 0, stream>>>(conv_w, conv_b, wfrag, wsum);
    k_conv_mfma<<<dim3(1024), dim3(256), 0, stream>>>(x, wfrag, wsum, conv_b,
                                                      D_out, Dsum);
    k_gauss<<<dim3(256), dim3(256), 0, stream>>>(Dsum, gaus_w, filt, g_out);
    k_sample<<<dim3(2048), dim3(128), 0, stream>>>(x, filt, y_out);
    (void)in_sizes; (void)n_in; (void)out_size; (void)ws_size;
}

// Round 5
// 120.192 us; speedup vs baseline: 4.8750x; 1.1276x over previous
//
#include <hip/hip_runtime.h>
#include <hip/hip_bf16.h>

// ---------------------------------------------------------------------------
// Def_DownSampling, round 5.
//  * gaus_w identical per (oc,ic) => gaussian path uses channel-summed field.
//  * conv3+avgpool folded to stride-2 4^3 conv (W4), exact algebra.
//  * D via bf16 MFMA; Dsum kept fp32 (fused VALU dot) for the grid path.
//  * R5: conv made barrier-free — wave-private LDS tiles (1z,1y,16x per wave),
//    2048 blocks x 2 waves for 8 blocks/CU; k_prep wsum parallelized
//    (lane-per-(k,oc) + shfl_xor tree).
// Outputs: y (2,32,32,32,32) | D (2,32,32,32,32) | grid-mean (2,32,32,32,3)
// ---------------------------------------------------------------------------

#define XN 64
#define DN 32
#define C  32
#define XVOL (XN * XN * XN)   // 262144
#define DVOL (DN * DN * DN)   // 32768

typedef __attribute__((ext_vector_type(8))) short short8v;
typedef __attribute__((ext_vector_type(4))) float float4v;

static __device__ __forceinline__ short f2bf(float f) {
    union { float f; unsigned u; } v; v.f = f;
    unsigned r = (v.u + 0x7fffu + ((v.u >> 16) & 1u)) >> 16;   // RNE
    return (short)r;
}

static __device__ __forceinline__ unsigned pk2(float a, float b) {
    __hip_bfloat162 h = __float22bfloat162_rn(float2{a, b});
    union { __hip_bfloat162 h2; unsigned u; } cv; cv.h2 = h;
    return cv.u;
}

// W4[ic][u][oc] = (1/8) sum_{s in {0,1}^3} conv_w[oc][ic][u-s]
static __device__ __forceinline__ float w4val(const float* __restrict__ conv_w,
                                              int ic, int u, int oc) {
    int uz = u >> 4, uy = (u >> 2) & 3, ux = u & 3;
    float s = 0.f;
    #pragma unroll
    for (int sz = 0; sz < 2; ++sz) {
        int tz = uz - sz; if (tz < 0 || tz > 2) continue;
        #pragma unroll
        for (int sy = 0; sy < 2; ++sy) {
            int ty = uy - sy; if (ty < 0 || ty > 2) continue;
            #pragma unroll
            for (int sx = 0; sx < 2; ++sx) {
                int tx = ux - sx; if (tx < 0 || tx > 2) continue;
                s += conv_w[(oc * C + ic) * 27 + tz * 9 + ty * 3 + tx];
            }
        }
    }
    return 0.125f * s;
}

// ---- K0: blocks 0..255 pack A-fragments (bf16) + biassum;
//          blocks 256..511 compute wsum[k] = sum_oc W4[k][oc] via shfl tree.
__global__ __launch_bounds__(256) void k_prep(const float* __restrict__ conv_w,
                                              const float* __restrict__ conv_b,
                                              unsigned short* __restrict__ wfrag,
                                              float* __restrict__ wsum) {
    int bid = blockIdx.x;
    int tid = threadIdx.x;
    if (bid < 256) {
        int i = bid * 256 + tid;                // 65536
        int e = i & 7;
        int l = (i >> 3) & 63;
        int sf = i >> 9;
        int f = sf & 1, step = sf >> 1;
        int oc = f * 16 + (l & 15);
        int k = step * 32 + ((l >> 4) * 8 + e);
        float v = w4val(conv_w, k >> 6, k & 63, oc);
        wfrag[i] = (unsigned short)f2bf(v);
        if (i == 0) {
            float s = 0.f;
            for (int o = 0; o < C; ++o) s += conv_b[o];
            wsum[2048] = s;
        }
    } else {
        int i2 = (bid - 256) * 256 + tid;       // 65536 = 2048 k x 32 oc
        int oc = tid & 31;
        int kk = i2 >> 5;
        float v = w4val(conv_w, kk >> 6, kk & 63, oc);
        v += __shfl_xor(v, 1, 64);
        v += __shfl_xor(v, 2, 64);
        v += __shfl_xor(v, 4, 64);
        v += __shfl_xor(v, 8, 64);
        v += __shfl_xor(v, 16, 64);
        if (oc == 0) wsum[kk] = v;
    }
}

// ---- K1: MFMA conv, barrier-free. 2048 blocks x 128 thr (2 waves).
// Wave = output (1z, 1y, 16x); private LDS tile 4z x 4y x 34x (stride 36).
#define WROWS 16            // 4z * 4y
#define WSTRIDE 36
#define WTILE (WROWS * WSTRIDE)   // 576 floats per buffer
#define NLD 544             // 4*4*34 staged floats per wave

__global__ __launch_bounds__(128) void k_conv_mfma(
        const float* __restrict__ x, const unsigned short* __restrict__ wfrag,
        const float* __restrict__ wsum, const float* __restrict__ bias,
        float* __restrict__ Dout, float* __restrict__ Dsum) {
    __shared__ float tile[2][2][WTILE];     // [wave][buf]
    int bid = blockIdx.x;
    int wid = (bid & 7) * 256 + (bid >> 3);     // XCD-chunked swizzle (2048%8==0)
    int xt = wid & 1;
    int yt = (wid >> 1) & 15;
    int zt = (wid >> 5) & 31;
    int b  = wid >> 10;
    int tid = threadIdx.x;
    int w = tid >> 6, lane = tid & 63;
    int col = lane & 15, g = lane >> 4;
    int pz = zt, py = yt * 2 + w, px = xt * 16 + col;

    int gz0 = 2 * pz - 1, gy0 = 2 * py - 1, gx0 = xt * 32 - 1;
    const float* xb_base = x + (size_t)b * C * XVOL;

    // hoisted (ic-invariant) staging index math: i = lane + it*64, i < 544
    int  soff[9], sdst[9];
    bool sval[9], swr[9];
    #pragma unroll
    for (int it = 0; it < 9; ++it) {
        int i = lane + it * 64;
        int lx = i % 34; int r = i / 34; int lz = r >> 2; int ly = r & 3;
        int gz = gz0 + lz, gy = gy0 + ly, gx = gx0 + lx;
        bool inr = i < NLD;
        swr[it]  = inr;
        sval[it] = inr && (unsigned)gz < XN && (unsigned)gy < XN && (unsigned)gx < XN;
        soff[it] = ((gz & 63) * XN + (gy & 63)) * XN + (gx & 63);
        sdst[it] = inr ? (lz * 4 + ly) * WSTRIDE + lx : 0;
    }

    // per-lane LDS read base: row = uz*4+uy; uz=(g>>1)+2h, uy=(g&1)*2(+1)
    int base_g = ((g >> 1) * 4 + (g & 1) * 2) * WSTRIDE + 2 * col;
    float* t0 = tile[w][0];
    float* t1 = tile[w][1];

    float4v acc0 = {0.f, 0.f, 0.f, 0.f};
    float4v acc1 = {0.f, 0.f, 0.f, 0.f};
    float dp = 0.f;

    {   // prologue: stage ic=0, preload ic=1 to regs
        float sv[9];
        #pragma unroll
        for (int it = 0; it < 9; ++it) sv[it] = sval[it] ? xb_base[soff[it]] : 0.f;
        #pragma unroll
        for (int it = 0; it < 9; ++it) if (swr[it]) t0[sdst[it]] = sv[it];
    }
    float svB[9];
    {
        const float* xp = xb_base + XVOL;
        #pragma unroll
        for (int it = 0; it < 9; ++it) svB[it] = sval[it] ? xp[soff[it]] : 0.f;
    }

    for (int ic = 0; ic < C; ++ic) {
        // write-late: svB holds ic+1 (loaded one iteration ago) -> other buffer
        float* dst = (ic & 1) ? t0 : t1;
        if (ic + 1 < C) {
            #pragma unroll
            for (int it = 0; it < 9; ++it) if (swr[it]) dst[sdst[it]] = svB[it];
        }
        // issue-early: loads for ic+2
        float svA[9];
        if (ic + 2 < C) {
            const float* xp = xb_base + (size_t)(ic + 2) * XVOL;
            #pragma unroll
            for (int it = 0; it < 9; ++it) svA[it] = sval[it] ? xp[soff[it]] : 0.f;
        }
        const float* t = (ic & 1) ? t1 : t0;
        #pragma unroll
        for (int h = 0; h < 2; ++h) {
            int step = ic * 2 + h;
            int off0 = base_g + h * 288;        // h advances uz by 2 -> 8 rows
            float2 v01 = *(const float2*)&t[off0];
            float2 v23 = *(const float2*)&t[off0 + 2];
            float2 v45 = *(const float2*)&t[off0 + WSTRIDE];
            float2 v67 = *(const float2*)&t[off0 + WSTRIDE + 2];
            float4v wlo = *(const float4v*)&wsum[step * 32 + g * 8];
            float4v whi = *(const float4v*)&wsum[step * 32 + g * 8 + 4];
            dp = fmaf(wlo.x, v01.x, dp); dp = fmaf(wlo.y, v01.y, dp);
            dp = fmaf(wlo.z, v23.x, dp); dp = fmaf(wlo.w, v23.y, dp);
            dp = fmaf(whi.x, v45.x, dp); dp = fmaf(whi.y, v45.y, dp);
            dp = fmaf(whi.z, v67.x, dp); dp = fmaf(whi.w, v67.y, dp);
            union { short8v s; unsigned u[4]; } B;
            B.u[0] = pk2(v01.x, v01.y);
            B.u[1] = pk2(v23.x, v23.y);
            B.u[2] = pk2(v45.x, v45.y);
            B.u[3] = pk2(v67.x, v67.y);
            short8v a0 = *(const short8v*)&wfrag[((size_t)(step * 2 + 0) * 64 + lane) * 8];
            short8v a1 = *(const short8v*)&wfrag[((size_t)(step * 2 + 1) * 64 + lane) * 8];
            acc0 = __builtin_amdgcn_mfma_f32_16x16x32_bf16(a0, B.s, acc0, 0, 0, 0);
            acc1 = __builtin_amdgcn_mfma_f32_16x16x32_bf16(a1, B.s, acc1, 0, 0, 0);
        }
        if (ic + 2 < C) {
            #pragma unroll
            for (int it = 0; it < 9; ++it) svB[it] = svA[it];
        }
    }

    dp += __shfl_xor(dp, 16, 64);
    dp += __shfl_xor(dp, 32, 64);

    int sp = pz * (DN * DN) + py * DN + px;
    float4v b0 = *(const float4v*)&bias[g * 4];
    float4v b1 = *(const float4v*)&bias[16 + g * 4];
    #pragma unroll
    for (int r = 0; r < 4; ++r) {
        int oc0 = g * 4 + r;
        int oc1 = 16 + g * 4 + r;
        Dout[(size_t)(b * C + oc0) * DVOL + sp] = acc0[r] + b0[r];
        Dout[(size_t)(b * C + oc1) * DVOL + sp] = acc1[r] + b1[r];
    }
    if (g == 0)
        Dsum[b * DVOL + sp] = dp + wsum[2048];
}

// ---- K2: 5^3 gaussian, LDS-staged. Block = (4z x 8y x 8x), 256 blocks.
__global__ __launch_bounds__(256) void k_gauss(const float* __restrict__ Dsum,
                                               const float* __restrict__ gaus_w,
                                               float* __restrict__ filt,
                                               float* __restrict__ outg) {
    __shared__ float tg[8 * 12 * 12];   // 1152
    __shared__ float gk[125];
    int bid = blockIdx.x;
    int xt = bid & 3, yt = (bid >> 2) & 3, zt = (bid >> 4) & 7, b = bid >> 7;
    int tid = threadIdx.x;
    if (tid < 125) gk[tid] = gaus_w[tid];   // replicated kernel: [0][0] slice
    const float* Ds = Dsum + b * DVOL;
    for (int i = tid; i < 1152; i += 256) {
        int lx = i % 12; int r = i / 12; int ly = r % 12; int lz = r / 12;
        int gz = zt * 4 - 2 + lz, gy = yt * 8 - 2 + ly, gx = xt * 8 - 2 + lx;
        float v = 0.f;
        if ((unsigned)gz < DN && (unsigned)gy < DN && (unsigned)gx < DN)
            v = Ds[(gz * DN + gy) * DN + gx];
        tg[i] = v;
    }
    __syncthreads();
    int px = tid & 7, py = (tid >> 3) & 7, pz = tid >> 6;
    const float inv31 = 1.f / 31.f;
    float zb = (float)(zt * 4 + pz - 2);
    float yb = (float)(yt * 8 + py - 2);
    float xb = (float)(xt * 8 + px - 2);
    float p = 0.f, a0 = 0.f, a1 = 0.f, a2 = 0.f;
    for (int tz = 0; tz < 5; ++tz)
    for (int ty = 0; ty < 5; ++ty) {
        int base = ((pz + tz) * 12 + py + ty) * 12 + px;
        #pragma unroll
        for (int tx = 0; tx < 5; ++tx) {
            float g = gk[tz * 25 + ty * 5 + tx];
            float v = g * tg[base + tx];
            p += v;
            a0 = fmaf(v, (zb + (float)tz) * inv31, a0);
            a1 = fmaf(v, (yb + (float)ty) * inv31, a1);
            a2 = fmaf(v, (xb + (float)tx) * inv31, a2);
        }
    }
    float denom = p + 1e-6f;
    float f0 = fminf(fmaxf(a0 / denom * 2.f - 1.f, -1.f), 1.f);
    float f1 = fminf(fmaxf(a1 / denom * 2.f - 1.f, -1.f), 1.f);
    float f2 = fminf(fmaxf(a2 / denom * 2.f - 1.f, -1.f), 1.f);
    int sp = ((zt * 4 + pz) * DN + yt * 8 + py) * DN + xt * 8 + px;
    filt[(b * 3 + 0) * DVOL + sp] = f0;
    filt[(b * 3 + 1) * DVOL + sp] = f1;
    filt[(b * 3 + 2) * DVOL + sp] = f2;
    outg[(size_t)(b * DVOL + sp) * 3 + 0] = f0;
    outg[(size_t)(b * DVOL + sp) * 3 + 1] = f1;
    outg[(size_t)(b * DVOL + sp) * 3 + 2] = f2;
}

// ---- K3: trilinear grid sample. 2048 blocks x 128 thr; tile (2z,4y,16x),
// 8 channels per block. XCD chunk = one (b, channel-group), z-major.
__global__ __launch_bounds__(128, 4) void k_sample(const float* __restrict__ x,
                                                   const float* __restrict__ filt,
                                                   float* __restrict__ y) {
    int bid = blockIdx.x;
    int wid = (bid & 7) * 256 + (bid >> 3);   // 2048%8==0, bijective chunk
    int xt = wid & 1;
    int yt = (wid >> 1) & 7;
    int zt = (wid >> 4) & 15;
    int cgrp = (wid >> 8) & 3;
    int b  = wid >> 10;
    int tid = threadIdx.x;
    int px = tid & 15, py = (tid >> 4) & 3, pz = tid >> 6;
    int sp = ((zt * 2 + pz) * DN + yt * 4 + py) * DN + xt * 16 + px;
    const float* fb = filt + b * 3 * DVOL;
    float g0 = fb[sp], g1 = fb[DVOL + sp], g2 = fb[2 * DVOL + sp];

    float ix = ((g0 + 1.0f) * (float)XN - 1.0f) * 0.5f;
    float iy = ((g1 + 1.0f) * (float)XN - 1.0f) * 0.5f;
    float iz = ((g2 + 1.0f) * (float)XN - 1.0f) * 0.5f;
    float x0f = floorf(ix), y0f = floorf(iy), z0f = floorf(iz);
    float wx = ix - x0f, wyf = iy - y0f, wz = iz - z0f;
    int x0 = (int)x0f, y0i = (int)y0f, z0 = (int)z0f;

    int offs[8];
    float wts[8];
    #pragma unroll
    for (int t = 0; t < 8; ++t) {
        int dz = t >> 2, dy = (t >> 1) & 1, dx = t & 1;
        int zc = z0 + dz, yc = y0i + dy, xc = x0 + dx;
        bool valid = (unsigned)zc < (unsigned)XN && (unsigned)yc < (unsigned)XN &&
                     (unsigned)xc < (unsigned)XN;
        int zcl = min(max(zc, 0), XN - 1);
        int ycl = min(max(yc, 0), XN - 1);
        int xcl = min(max(xc, 0), XN - 1);
        offs[t] = zcl * (XN * XN) + ycl * XN + xcl;
        float w = (dz ? wz : 1.f - wz) * (dy ? wyf : 1.f - wyf) * (dx ? wx : 1.f - wx);
        wts[t] = valid ? w : 0.f;
    }

    const float* xc0 = x + (size_t)(b * C + cgrp * 8) * XVOL;
    #pragma unroll
    for (int g = 0; g < 2; ++g) {
        float t[4][8];                       // 32 loads in flight
        #pragma unroll
        for (int j = 0; j < 4; ++j) {
            const float* xb = xc0 + (size_t)(g * 4 + j) * XVOL;
            #pragma unroll
            for (int k = 0; k < 8; ++k) t[j][k] = xb[offs[k]];
        }
        #pragma unroll
        for (int j = 0; j < 4; ++j) {
            float acc = 0.f;
            #pragma unroll
            for (int k = 0; k < 8; ++k) acc = fmaf(wts[k], t[j][k], acc);
            y[(size_t)(b * C + cgrp * 8 + g * 4 + j) * DVOL + sp] = acc;
        }
    }
}

extern "C" void kernel_launch(void* const* d_in, const int* in_sizes, int n_in,
                              void* d_out, int out_size, void* d_ws, size_t ws_size,
                              hipStream_t stream) {
    const float* x      = (const float*)d_in[0];
    const float* conv_w = (const float*)d_in[1];
    const float* conv_b = (const float*)d_in[2];
    const float* gaus_w = (const float*)d_in[3];

    float* out = (float*)d_out;
    float* y_out = out;
    float* D_out = out + (size_t)2097152;
    float* g_out = out + (size_t)4194304;

    float* ws   = (float*)d_ws;
    float* Dsum = ws;                         // 65536 f
    float* filt = ws + 65536;                 // 196608 f
    float* wsum = ws + 262144;                // 2049 f (+pad)
    unsigned short* wfrag = (unsigned short*)(ws + 264256);  // 65536 u16

    k_prep<<<dim3(512), dim3(256), 0, stream>>>(conv_w, conv_b, wfrag, wsum);
    k_conv_mfma<<<dim3(2048), dim3(128), 0, stream>>>(x, wfrag, wsum, conv_b,
                                                      D_out, Dsum);
    k_gauss<<<dim3(256), dim3(256), 0, stream>>>(Dsum, gaus_w, filt, g_out);
    k_sample<<<dim3(2048), dim3(128), 0, stream>>>(x, filt, y_out);
    (void)in_sizes; (void)n_in; (void)out_size; (void)ws_size;
}